// Round 6
// baseline (48.212 us; speedup 1.0000x reference)
//
#include <hip/hip_runtime.h>

#define B_N   2048
#define LQ    10
#define LH    150

typedef float f4 __attribute__((ext_vector_type(4)));

// LDS arena (floats), row stride 20 (8 row-groups -> exact 2-way bank aliasing):
//   XS  [0,720)    : padded X, ch*360 + y*20 + x
//   RP  [720,1080) : padded r
//   VP  [1080,1800): double-buffered padded v (VP+0 / VP+360)
//   WL  [1800,1920): VI weights padded to 12 floats/action (16B-aligned)
//   EF  [1920,1948): [0..17] eff_w, [18] eff_b, [19..27] fw
//   SCR [1948,2076): reduction scratch (one slot per thread)
#define XS    0
#define RP    720
#define VP    1080
#define WL    1800
#define EF    1920
#define SCR   1948
#define SMEMN 2080

// 2 waves (128 thr) per batch element; tid = rg*16 + c, rg=0..7 owns rows
// 2rg,2rg+1, col c. 2048 blocks * 2 waves = 4 waves/SIMD (2x the latency
// hiding of the 1-wave version whose VALUBusy was stuck at 41%).
// VI weights live in LDS and are re-read per action as 3 broadcast
// ds_read_b128 (conflict-free), keeping per-lane VGPRs under the 4-wave cap.
// No runtime indexing into any register array (round-4 lesson).
__global__ __launch_bounds__(128, 4) void vin_kernel(
    const float* __restrict__ X,   const float* __restrict__ S1,
    const float* __restrict__ S2,  const float* __restrict__ h_w,
    const float* __restrict__ h_b, const float* __restrict__ r_w,
    const float* __restrict__ qw,  const float* __restrict__ w,
    const float* __restrict__ fcw, float* __restrict__ out)
{
    __shared__ float smem[SMEMN];

    const int b   = blockIdx.x;
    const int tid = threadIdx.x;
    const int rg  = tid >> 4;     // 0..7
    const int c   = tid & 15;

    // ---- issue X loads first ----
    const float* Xb = X + (size_t)b * 512;
    float xreg[4];
    #pragma unroll
    for (int k = 0; k < 4; ++k) xreg[k] = Xb[tid + (k << 7)];

    // ---- zero arena (conv borders + wlds pads must be 0) ----
    #pragma unroll
    for (int k = 0; k < 17; ++k) {
        int idx = tid + (k << 7);
        if (idx < SMEMN) smem[idx] = 0.f;
    }

    // ---- collapsed-weight partials (registers only before sync) ----
    float part = 0.f;
    if (tid < 54) {
        const int t  = tid / 3;
        const int h0 = (tid - t * 3) * 50;
        for (int h = h0; h < h0 + 50; ++h) part += r_w[h] * h_w[h * 18 + t];
    } else if (tid < 57) {
        const int h0 = (tid - 54) * 50;
        for (int h = h0; h < h0 + 50; ++h) part += r_w[h] * h_b[h];
    }
    __syncthreads();                       // zero-fill visible

    smem[SCR + tid] = part;

    // stage X into padded LDS
    #pragma unroll
    for (int k = 0; k < 4; ++k) {
        int e = tid + (k << 7);
        int ch = e >> 8, rem = e & 255;
        smem[XS + ch * 360 + ((rem >> 4) + 1) * 20 + (rem & 15) + 1] = xreg[k];
    }
    // copy VI weights -> LDS, padded stride 12
    {
        int j = -1;
        if (tid >= 64)      j = tid - 64;      // 0..63
        else if (tid < 26)  j = 64 + tid;      // 64..89
        if (j >= 0) {
            int a = j / 9, t = j - a * 9;
            smem[WL + a * 12 + t] = w[j];
        }
    }
    // fw[t] = sum_a fc_w[a]*w[a][t]
    if (tid >= 57 && tid < 66) {
        const int t = tid - 57;
        float acc = 0.f;
        #pragma unroll
        for (int a = 0; a < LQ; ++a) acc += fcw[a] * w[a * 9 + t];
        smem[EF + 19 + t] = acc;
    }
    __syncthreads();

    if (tid < 18)
        smem[EF + tid] = smem[SCR + tid * 3] + smem[SCR + tid * 3 + 1] + smem[SCR + tid * 3 + 2];
    else if (tid == 18)
        smem[EF + 18] = smem[SCR + 54] + smem[SCR + 55] + smem[SCR + 56];
    __syncthreads();

    // ---- r = conv3x3(X, eff_w) + eff_b for this lane's 2 rows ----
    float ew[19];
    #pragma unroll
    for (int t = 0; t < 19; ++t) ew[t] = smem[EF + t];

    float xt[2][4][3];
    #pragma unroll
    for (int ch = 0; ch < 2; ++ch)
        #pragma unroll
        for (int dy = 0; dy < 4; ++dy)
            #pragma unroll
            for (int dx = 0; dx < 3; ++dx)
                xt[ch][dy][dx] = smem[XS + ch * 360 + ((rg << 1) + dy) * 20 + c + dx];

    #pragma unroll
    for (int k = 0; k < 2; ++k) {
        float acc = ew[18];
        #pragma unroll
        for (int ch = 0; ch < 2; ++ch)
            #pragma unroll
            for (int ky = 0; ky < 3; ++ky)
                #pragma unroll
                for (int kx = 0; kx < 3; ++kx)
                    acc += xt[ch][k + ky][kx] * ew[ch * 9 + ky * 3 + kx];
        smem[RP + ((rg << 1) + k + 1) * 20 + c + 1] = acc;
    }
    __syncthreads();

    // ---- qr[k][a] = conv3x3(r, q_w)[a] (iteration-invariant half) ----
    float rt[4][3];
    #pragma unroll
    for (int dy = 0; dy < 4; ++dy)
        #pragma unroll
        for (int dx = 0; dx < 3; ++dx)
            rt[dy][dx] = smem[RP + ((rg << 1) + dy) * 20 + c + dx];

    float qr[2][LQ];
    #pragma unroll
    for (int a = 0; a < LQ; ++a) {
        #pragma unroll
        for (int k = 0; k < 2; ++k) {
            float acc = 0.f;
            #pragma unroll
            for (int ky = 0; ky < 3; ++ky)
                #pragma unroll
                for (int kx = 0; kx < 3; ++kx)
                    acc += rt[k + ky][kx] * qw[a * 9 + ky * 3 + kx];
            qr[k][a] = acc;
        }
    }

    // ---- v0 = max_a qr ----
    #pragma unroll
    for (int k = 0; k < 2; ++k) {
        float m = qr[k][0];
        #pragma unroll
        for (int a = 1; a < LQ; ++a) m = fmaxf(m, qr[k][a]);
        smem[VP + 0 + ((rg << 1) + k + 1) * 20 + c + 1] = m;
    }
    __syncthreads();

    // ---- 19 VI sweeps; w re-read per action as 3 broadcast ds_read_b128 ----
#define VSTEP(SRC, DST)                                                        \
    {                                                                          \
        float vt[4][3];                                                        \
        _Pragma("unroll")                                                      \
        for (int dy = 0; dy < 4; ++dy)                                         \
            _Pragma("unroll")                                                  \
            for (int dx = 0; dx < 3; ++dx)                                     \
                vt[dy][dx] = smem[VP + (SRC) + ((rg << 1) + dy) * 20 + c + dx];\
        float m0, m1;                                                          \
        _Pragma("unroll")                                                      \
        for (int a = 0; a < LQ; ++a) {                                         \
            const f4* wq = (const f4*)&smem[WL + a * 12];                      \
            f4 A = wq[0], Bq = wq[1], Cq = wq[2];                              \
            float a0 = qr[0][a], a1 = qr[1][a];                                \
            a0 += vt[0][0]*A.x + vt[0][1]*A.y + vt[0][2]*A.z;                  \
            a1 += vt[1][0]*A.x + vt[1][1]*A.y + vt[1][2]*A.z;                  \
            a0 += vt[1][0]*A.w + vt[1][1]*Bq.x + vt[1][2]*Bq.y;                \
            a1 += vt[2][0]*A.w + vt[2][1]*Bq.x + vt[2][2]*Bq.y;                \
            a0 += vt[2][0]*Bq.z + vt[2][1]*Bq.w + vt[2][2]*Cq.x;               \
            a1 += vt[3][0]*Bq.z + vt[3][1]*Bq.w + vt[3][2]*Cq.x;               \
            if (a == 0) { m0 = a0; m1 = a1; }                                  \
            else        { m0 = fmaxf(m0, a0); m1 = fmaxf(m1, a1); }            \
        }                                                                      \
        smem[VP + (DST) + ((rg << 1) + 1) * 20 + c + 1] = m0;                  \
        smem[VP + (DST) + ((rg << 1) + 2) * 20 + c + 1] = m1;                  \
        __syncthreads();                                                       \
    }

    #pragma unroll 1
    for (int it = 0; it < 9; ++it) {
        VSTEP(0, 360)
        VSTEP(360, 0)
    }
    VSTEP(0, 360)   // step 19; final v in VP+360

    // ---- final conv + gather + fc at (s1, s2) only ----
    const float s1f = S1[b], s2f = S2[b];
    int s1 = (int)floorf((s1f + 50.0f) / 6.25f);
    int s2 = (int)floorf((s2f + 50.0f) / 6.25f);
    s1 = min(max(s1, 0), 15);
    s2 = min(max(s2, 0), 15);

    if (rg == (s1 >> 1) && c == s2) {
        float d0 = 0.f, d1 = 0.f;
        #pragma unroll
        for (int a = 0; a < LQ; ++a) {
            d0 += fcw[a] * qr[0][a];
            d1 += fcw[a] * qr[1][a];
        }
        float logit = ((s1 & 1) == 0) ? d0 : d1;
        #pragma unroll
        for (int ky = 0; ky < 3; ++ky)
            #pragma unroll
            for (int kx = 0; kx < 3; ++kx)
                logit += smem[VP + 360 + (s1 + ky) * 20 + s2 + kx] * smem[EF + 19 + ky * 3 + kx];
        out[b]       = logit;   // logits
        out[B_N + b] = 1.0f;    // softmax over length-1 axis == 1
    }
#undef VSTEP
}

extern "C" void kernel_launch(void* const* d_in, const int* in_sizes, int n_in,
                              void* d_out, int out_size, void* d_ws, size_t ws_size,
                              hipStream_t stream) {
    const float* X    = (const float*)d_in[0];
    const float* S1   = (const float*)d_in[1];
    const float* S2   = (const float*)d_in[2];
    const float* h_w  = (const float*)d_in[3];
    const float* h_b  = (const float*)d_in[4];
    const float* r_w  = (const float*)d_in[5];
    const float* q_w  = (const float*)d_in[6];
    const float* w    = (const float*)d_in[7];
    const float* fc_w = (const float*)d_in[8];
    float*       out  = (float*)d_out;

    vin_kernel<<<B_N, 128, 0, stream>>>(X, S1, S2, h_w, h_b, r_w, q_w, w, fc_w, out);
}